// Round 1
// baseline (200.790 us; speedup 1.0000x reference)
//
#include <hip/hip_runtime.h>

#define B_    1024
#define TI_   2
#define TE_   3
#define BIN_  16
#define BOUT_ 32

// out[n,ab,o,l,k] = sum_i X[n,ab,i,l] * W[ab,i,o,k]   (+bias for NSH==1)
// Block: one (n, ab). Wave lane = (o, ktile): o = lane>>1, k0 = wave*8 + (lane&1)*4.
// Lane computes acc[NSH][4] (all l, 4 k). Stage tile in LDS, flush with float4.
template<int NSH, int KW>
__global__ __launch_bounds__(KW * 64)
void s2conv_kernel(const float* __restrict__ X, const float* __restrict__ W,
                   const float* __restrict__ bias, float* __restrict__ OUT) {
    constexpr int NOUT = BOUT_ * NSH * NSH;
    __shared__ __align__(16) float lds[NOUT];

    const int tid  = threadIdx.x;
    const int wave = tid >> 6;
    const int lane = tid & 63;
    const int o    = lane >> 1;
    const int k0   = wave * 8 + (lane & 1) * 4;
    const int n    = blockIdx.x;
    const int ab   = blockIdx.y;

    const float* Xp = X + (size_t)(n * (TI_ * TE_) + ab) * BIN_ * NSH;
    const float* Wp = W + ((size_t)ab * BIN_ * BOUT_ + o) * NSH;

    float bv = 0.0f;
    if (NSH == 1) bv = bias[ab * BOUT_ + o];

    float acc[NSH][4];
#pragma unroll
    for (int l = 0; l < NSH; ++l)
#pragma unroll
        for (int kk = 0; kk < 4; ++kk) acc[l][kk] = bv;

#pragma unroll 4
    for (int i = 0; i < BIN_; ++i) {
        float xv[NSH];
#pragma unroll
        for (int l = 0; l < NSH; ++l) xv[l] = Xp[i * NSH + l];  // wave-uniform broadcast
        float wv[4];
#pragma unroll
        for (int kk = 0; kk < 4; ++kk) {
            int k = k0 + kk;
            if (k > NSH - 1) k = NSH - 1;  // clamp: tail lanes load a valid addr, never stored
            wv[kk] = Wp[i * (BOUT_ * NSH) + k];
        }
#pragma unroll
        for (int l = 0; l < NSH; ++l)
#pragma unroll
            for (int kk = 0; kk < 4; ++kk)
                acc[l][kk] = fmaf(xv[l], wv[kk], acc[l][kk]);
    }

    // stage (o,l,k) tile in LDS; o-stride = NSH*NSH words (odd) -> conflict-light
#pragma unroll
    for (int l = 0; l < NSH; ++l)
#pragma unroll
        for (int kk = 0; kk < 4; ++kk) {
            int k = k0 + kk;
            if (k < NSH) lds[(o * NSH + l) * NSH + k] = acc[l][kk];
        }
    __syncthreads();

    // flat, fully-coalesced float4 flush (NOUT divisible by 4; bases 16B-aligned)
    float4* dst = (float4*)(OUT + (size_t)(n * (TI_ * TE_) + ab) * NOUT);
    const float4* src = (const float4*)lds;
    constexpr int NC = NOUT / 4;
    for (int c = tid; c < NC; c += KW * 64) dst[c] = src[c];
}

extern "C" void kernel_launch(void* const* d_in, const int* in_sizes, int n_in,
                              void* d_out, int out_size, void* d_ws, size_t ws_size,
                              hipStream_t stream) {
    const float* x0 = (const float*)d_in[0];
    const float* w0 = (const float*)d_in[1];
    const float* x2 = (const float*)d_in[2];
    const float* w2 = (const float*)d_in[3];
    const float* x4 = (const float*)d_in[4];
    const float* w4 = (const float*)d_in[5];
    const float* x6 = (const float*)d_in[6];
    const float* w6 = (const float*)d_in[7];
    const float* x8 = (const float*)d_in[8];
    const float* w8 = (const float*)d_in[9];
    const float* bias = (const float*)d_in[10];
    float* out = (float*)d_out;

    const size_t per = (size_t)B_ * TI_ * TE_ * BOUT_;  // per-(l,k) element count
    size_t off0 = 0;
    size_t off2 = off0 + per * 1 * 1;
    size_t off4 = off2 + per * 5 * 5;
    size_t off6 = off4 + per * 9 * 9;
    size_t off8 = off6 + per * 13 * 13;

    dim3 grid(B_, TI_ * TE_);
    s2conv_kernel<1, 1><<<grid, 64, 0, stream>>>(x0, w0, bias, out + off0);
    s2conv_kernel<5, 1><<<grid, 64, 0, stream>>>(x2, w2, bias, out + off2);
    s2conv_kernel<9, 2><<<grid, 128, 0, stream>>>(x4, w4, bias, out + off4);
    s2conv_kernel<13, 2><<<grid, 128, 0, stream>>>(x6, w6, bias, out + off6);
    s2conv_kernel<17, 3><<<grid, 192, 0, stream>>>(x8, w8, bias, out + off8);
}